// Round 9
// baseline (58.643 us; speedup 1.0000x reference)
//
#include <hip/hip_runtime.h>

// Lucas-Kanade optical flow — r9: r7 verbatim, single change:
// __launch_bounds__(256,8) -> 8 blocks/CU resident (was 4). A/B test of the
// latency/occupancy theory. Math/order identical to r7 (absmax 0.0078125).
// Input:  image_prev, image_next  (1,1,2048,2048) fp32
// Output: (1,2,2048,2048) fp32  -> u at [0:H*W], v at [H*W:2*H*W]

#pragma clang fp contract(off)

#define IMG_H 2048
#define IMG_W 2048
#define TW 32
#define TH 32
// LDS col c holds res at image col (c0 + c - 1): 0 = left halo, 1..32 interior,
// 33 = right halo, 34 = pad. stride 35 (odd) -> bank = 3*row + col: 2-way, free.
#define LDSW 35

__global__ __launch_bounds__(256, 8)
void lk_flow_v9(const float* __restrict__ prev,
                const float* __restrict__ next,
                float* __restrict__ out) {
    #pragma clang fp contract(off)
    __shared__ float srx[(TH + 2) * LDSW];
    __shared__ float sry[(TH + 2) * LDSW];
    __shared__ float srt[(TH + 2) * LDSW];

    // XCD-aware remap (r6): each XCD gets a contiguous band of 8 tile-rows.
    const int lin = (int)blockIdx.y * (int)gridDim.x + (int)blockIdx.x;
    const int nl  = (lin >> 3) + (lin & 7) * 512;
    const int r0  = (nl >> 6) * TH;
    const int c0  = (nl & 63) * TW;

    const int tx  = (int)threadIdx.x;   // 0..7
    const int ty  = (int)threadIdx.y;   // 0..31
    const int tid = ty * 8 + tx;

    // rows touched: r0-1 .. r0+33 (incl. a1); cols touched: c0-1 .. c0+33
    const bool interior = (r0 > 0) & (r0 + TH + 2 <= IMG_H - 1) &
                          (c0 > 0) & (c0 + TW + 2 <= IMG_W - 1);

    if (interior) {
        // ---- fast Phase A: no bounds checks, no reflect, int32 addressing ----
        #pragma unroll
        for (int pass = 0; pass < 2; ++pass) {
            const int t = tid + pass * 256;
            if (pass == 0 || tid < 16) {          // 34*8 = 272 chunks
                const int hr = t >> 3;
                const int ch = t & 7;
                const int i0 = (r0 - 1 + hr) * IMG_W + (c0 + ch * 4);
                const int i1 = i0 + IMG_W;
                const float4 P0 = *reinterpret_cast<const float4*>(prev + i0);
                const float4 P1 = *reinterpret_cast<const float4*>(prev + i1);
                const float4 Q0 = *reinterpret_cast<const float4*>(next + i0);
                const float4 Q1 = *reinterpret_cast<const float4*>(next + i1);
                const float p0[5] = {P0.x, P0.y, P0.z, P0.w, prev[i0 + 4]};
                const float p1[5] = {P1.x, P1.y, P1.z, P1.w, prev[i1 + 4]};
                const float q0[5] = {Q0.x, Q0.y, Q0.z, Q0.w, next[i0 + 4]};
                const float q1[5] = {Q1.x, Q1.y, Q1.z, Q1.w, next[i1 + 4]};
                const int base = hr * LDSW + 1 + ch * 4;
                #pragma unroll
                for (int k = 0; k < 4; ++k) {
                    // bit-equal to reference left-to-right order:
                    //   gx=((p01-p00)-p10)+p11; gy=(p10-(p00+p01))+p11; gs=((p00+p01)+p10)+p11
                    const float Ap = p0[k] + p0[k + 1];
                    const float Aq = q0[k] + q0[k + 1];
                    const float gxp = ((p0[k + 1] - p0[k]) - p1[k]) + p1[k + 1];
                    const float gxq = ((q0[k + 1] - q0[k]) - q1[k]) + q1[k + 1];
                    const float gyp = (p1[k] - Ap) + p1[k + 1];
                    const float gyq = (q1[k] - Aq) + q1[k + 1];
                    const float gsp = (Ap + p1[k]) + p1[k + 1];
                    const float gsq = (Aq + q1[k]) + q1[k + 1];
                    srx[base + k] = 0.5f * (gxp + gxq);
                    sry[base + k] = 0.5f * (gyp + gyq);
                    srt[base + k] = 0.5f * (gsq - gsp);     // 0.5*(-gsp+gsq)
                }
            }
        }
        if (tid < 68) {   // edge cols: e=0 -> image c0-1 (LDS 0), e=1 -> c0+32 (LDS 33)
            const int hr = tid >> 1;
            const int e  = tid & 1;
            const int bc = e ? (c0 + TW) : (c0 - 1);
            const int i0 = (r0 - 1 + hr) * IMG_W + bc;
            const int i1 = i0 + IMG_W;
            const float p00 = prev[i0], p01 = prev[i0 + 1];
            const float p10 = prev[i1], p11 = prev[i1 + 1];
            const float q00 = next[i0], q01 = next[i0 + 1];
            const float q10 = next[i1], q11 = next[i1 + 1];
            const float Ap = p00 + p01, Aq = q00 + q01;
            const float gxp = ((p01 - p00) - p10) + p11;
            const float gxq = ((q01 - q00) - q10) + q11;
            const float gyp = (p10 - Ap) + p11;
            const float gyq = (q10 - Aq) + q11;
            const float gsp = (Ap + p10) + p11;
            const float gsq = (Aq + q10) + q11;
            const int o = hr * LDSW + (e ? 33 : 0);
            srx[o] = 0.5f * (gxp + gxq);
            sry[o] = 0.5f * (gyp + gyq);
            srt[o] = 0.5f * (gsq - gsp);
        }
    } else {
        // ---- slow Phase A: full bounds + reflect, scalar per LDS cell ----
        for (int t = tid; t < 34 * 34; t += 256) {
            const int hr = t / 34;
            const int c  = t - hr * 34;
            const int a  = r0 - 1 + hr;
            const int bc = c0 - 1 + c;
            float rx = 0.f, ry = 0.f, rt = 0.f;
            if (a >= 0 && a < IMG_H && bc >= 0 && bc < IMG_W) {
                const int a1 = (a + 1 == IMG_H) ? (IMG_H - 2) : (a + 1);   // reflect (after)
                const int b1 = (bc + 1 == IMG_W) ? (IMG_W - 2) : (bc + 1); // reflect (after)
                const int i0 = a * IMG_W, i1 = a1 * IMG_W;
                const float p00 = prev[i0 + bc], p01 = prev[i0 + b1];
                const float p10 = prev[i1 + bc], p11 = prev[i1 + b1];
                const float q00 = next[i0 + bc], q01 = next[i0 + b1];
                const float q10 = next[i1 + bc], q11 = next[i1 + b1];
                const float Ap = p00 + p01, Aq = q00 + q01;
                const float gxp = ((p01 - p00) - p10) + p11;
                const float gxq = ((q01 - q00) - q10) + q11;
                const float gyp = (p10 - Ap) + p11;
                const float gyq = (q10 - Aq) + q11;
                const float gsp = (Ap + p10) + p11;
                const float gsq = (Aq + q10) + q11;
                rx = 0.5f * (gxp + gxq);
                ry = 0.5f * (gyp + gyq);
                rt = 0.5f * (gsq - gsp);
            }
            const int o = hr * LDSW + c;
            srx[o] = rx; sry[o] = ry; srt[o] = rt;
        }
    }

    __syncthreads();

    // ---- Phase B: each thread -> 1 output row x 4 output cols ----
    const int jb = tx * 4;
    int off = ty * LDSW + jb;

    float aXX[4] = {0.f, 0.f, 0.f, 0.f};
    float aYY[4] = {0.f, 0.f, 0.f, 0.f};
    float aXY[4] = {0.f, 0.f, 0.f, 0.f};
    float aXT[4] = {0.f, 0.f, 0.f, 0.f};
    float aYT[4] = {0.f, 0.f, 0.f, 0.f};

    #pragma unroll
    for (int rr = 0; rr < 3; ++rr) {
        const float* px = srx + off;
        const float* py = sry + off;
        const float* pt = srt + off;
        float X[6], Y[6], T[6];
        #pragma unroll
        for (int k = 0; k < 6; ++k) { X[k] = px[k]; Y[k] = py[k]; T[k] = pt[k]; }
        off += LDSW;
        float xx[6], yy[6], xy[6], xt[6], yt[6];
        #pragma unroll
        for (int k = 0; k < 6; ++k) {
            xx[k] = X[k] * X[k];
            yy[k] = Y[k] * Y[k];
            xy[k] = X[k] * Y[k];
            xt[k] = T[k] * X[k];
            yt[k] = T[k] * Y[k];
        }
        // exact reference box3 order per output & array: dr outer (rr asc), dc inner
        #pragma unroll
        for (int q = 0; q < 4; ++q) {
            aXX[q] += xx[q]; aXX[q] += xx[q + 1]; aXX[q] += xx[q + 2];
            aYY[q] += yy[q]; aYY[q] += yy[q + 1]; aYY[q] += yy[q + 2];
            aXY[q] += xy[q]; aXY[q] += xy[q + 1]; aXY[q] += xy[q + 2];
            aXT[q] += xt[q]; aXT[q] += xt[q + 1]; aXT[q] += xt[q + 2];
            aYT[q] += yt[q]; aYT[q] += yt[q + 1]; aYT[q] += yt[q + 2];
        }
    }

    const int i = r0 + ty;
    float uo[4], vo[4];
    #pragma unroll
    for (int q = 0; q < 4; ++q) {
        const float Sxx = aXX[q], Syy = aYY[q], Sxy = aXY[q];
        const float Sxt = aXT[q], Syt = aYT[q];
        const float t1 = Sxx * Syy;
        const float t2 = Sxy * Sxy;
        const float det = t1 - t2;
        float u = 0.f, v = 0.f;
        if (det != 0.f) {
            const float inv = __builtin_amdgcn_rcpf(det);  // 1-ulp rcp, ample margin
            const float n1 = Syy * Sxt - Sxy * Syt;
            const float n2 = Sxx * Syt - Sxy * Sxt;
            u = n1 * inv;
            v = n2 * inv;
        }
        const int j = c0 + jb + q;
        if (i == 0 || j == 0) { u = 0.f; v = 0.f; }  // reference zeroes row0/col0
        uo[q] = u; vo[q] = v;
    }
    const int oidx = i * IMG_W + (c0 + jb);
    float4 U = {uo[0], uo[1], uo[2], uo[3]};
    float4 V = {vo[0], vo[1], vo[2], vo[3]};
    *reinterpret_cast<float4*>(out + oidx) = U;
    *reinterpret_cast<float4*>(out + IMG_H * IMG_W + oidx) = V;
}

extern "C" void kernel_launch(void* const* d_in, const int* in_sizes, int n_in,
                              void* d_out, int out_size, void* d_ws, size_t ws_size,
                              hipStream_t stream) {
    const float* prev = (const float*)d_in[0];
    const float* next = (const float*)d_in[1];
    float* out = (float*)d_out;
    dim3 grid(IMG_W / TW, IMG_H / TH);   // 64 x 64
    dim3 block(8, 32);
    lk_flow_v9<<<grid, block, 0, stream>>>(prev, next, out);
}

// Round 10
// 26.373 us; speedup vs baseline: 2.2236x; 2.2236x over previous
//
#include <hip/hip_runtime.h>

// Lucas-Kanade optical flow — r10: 64-wide tiles to cut HBM read amplification
// (r9 profile: kernel is HBM-bound at ~6.2 TB/s on 64MB fetch vs 33.5 ideal;
// 34-col tile rows had 1.8x cache-line amplification). TW=64 -> 1.19x.
// (256,4) kept: r9 proved 8 blocks/CU thrashes L2 (58.6us). Per-pixel op and
// rounding order identical to r7 (verified absmax 0.0078125).
// Input:  image_prev, image_next  (1,1,2048,2048) fp32
// Output: (1,2,2048,2048) fp32  -> u at [0:H*W], v at [H*W:2*H*W]

#pragma clang fp contract(off)

#define IMG_H 2048
#define IMG_W 2048
#define TW 64
#define TH 32
// LDS col c holds res at image col (c0 + c - 1): 0 = left halo, 1..64 interior,
// 65 = right halo, 66 = pad. stride 67 (odd) -> bank = 3*row + col: <=2-way, free.
#define LDSW 67

__global__ __launch_bounds__(256, 4)
void lk_flow_v10(const float* __restrict__ prev,
                 const float* __restrict__ next,
                 float* __restrict__ out) {
    #pragma clang fp contract(off)
    __shared__ float srx[(TH + 2) * LDSW];
    __shared__ float sry[(TH + 2) * LDSW];
    __shared__ float srt[(TH + 2) * LDSW];

    // XCD-aware remap: 2048 blocks -> 256 per XCD = 8 contiguous tile-rows
    // of 32 tile-cols each (row-major sweep within the band).
    const int lin = (int)blockIdx.y * (int)gridDim.x + (int)blockIdx.x;
    const int nl  = (lin >> 3) + (lin & 7) * 256;
    const int r0  = (nl >> 5) * TH;
    const int c0  = (nl & 31) * TW;

    const int tx  = (int)threadIdx.x;   // 0..7
    const int ty  = (int)threadIdx.y;   // 0..31
    const int tid = ty * 8 + tx;

    // rows touched: r0-1 .. r0+TH+1 (incl. a1); cols touched: c0-1 .. c0+TW+1
    const bool interior = (r0 > 0) & (r0 + TH + 2 <= IMG_H - 1) &
                          (c0 > 0) & (c0 + TW + 2 <= IMG_W - 1);

    if (interior) {
        // ---- fast Phase A: no bounds checks, no reflect, int32 addressing ----
        // (TH+2) rows x 16 four-col chunks = 544 chunks: 2 full passes + 32
        #pragma unroll
        for (int pass = 0; pass < 3; ++pass) {
            const int t = tid + pass * 256;
            if (pass < 2 || tid < 32) {
                const int hr = t >> 4;
                const int ch = t & 15;
                const int i0 = (r0 - 1 + hr) * IMG_W + (c0 + ch * 4);
                const int i1 = i0 + IMG_W;
                const float4 P0 = *reinterpret_cast<const float4*>(prev + i0);
                const float4 P1 = *reinterpret_cast<const float4*>(prev + i1);
                const float4 Q0 = *reinterpret_cast<const float4*>(next + i0);
                const float4 Q1 = *reinterpret_cast<const float4*>(next + i1);
                const float p0[5] = {P0.x, P0.y, P0.z, P0.w, prev[i0 + 4]};
                const float p1[5] = {P1.x, P1.y, P1.z, P1.w, prev[i1 + 4]};
                const float q0[5] = {Q0.x, Q0.y, Q0.z, Q0.w, next[i0 + 4]};
                const float q1[5] = {Q1.x, Q1.y, Q1.z, Q1.w, next[i1 + 4]};
                const int base = hr * LDSW + 1 + ch * 4;
                #pragma unroll
                for (int k = 0; k < 4; ++k) {
                    // bit-equal to reference left-to-right order:
                    //   gx=((p01-p00)-p10)+p11; gy=(p10-(p00+p01))+p11; gs=((p00+p01)+p10)+p11
                    const float Ap = p0[k] + p0[k + 1];
                    const float Aq = q0[k] + q0[k + 1];
                    const float gxp = ((p0[k + 1] - p0[k]) - p1[k]) + p1[k + 1];
                    const float gxq = ((q0[k + 1] - q0[k]) - q1[k]) + q1[k + 1];
                    const float gyp = (p1[k] - Ap) + p1[k + 1];
                    const float gyq = (q1[k] - Aq) + q1[k + 1];
                    const float gsp = (Ap + p1[k]) + p1[k + 1];
                    const float gsq = (Aq + q1[k]) + q1[k + 1];
                    srx[base + k] = 0.5f * (gxp + gxq);
                    sry[base + k] = 0.5f * (gyp + gyq);
                    srt[base + k] = 0.5f * (gsq - gsp);     // 0.5*(-gsp+gsq)
                }
            }
        }
        if (tid < (TH + 2) * 2) {   // 68 edge cells: e=0 -> c0-1 (LDS 0), e=1 -> c0+64 (LDS 65)
            const int hr = tid >> 1;
            const int e  = tid & 1;
            const int bc = e ? (c0 + TW) : (c0 - 1);
            const int i0 = (r0 - 1 + hr) * IMG_W + bc;
            const int i1 = i0 + IMG_W;
            const float p00 = prev[i0], p01 = prev[i0 + 1];
            const float p10 = prev[i1], p11 = prev[i1 + 1];
            const float q00 = next[i0], q01 = next[i0 + 1];
            const float q10 = next[i1], q11 = next[i1 + 1];
            const float Ap = p00 + p01, Aq = q00 + q01;
            const float gxp = ((p01 - p00) - p10) + p11;
            const float gxq = ((q01 - q00) - q10) + q11;
            const float gyp = (p10 - Ap) + p11;
            const float gyq = (q10 - Aq) + q11;
            const float gsp = (Ap + p10) + p11;
            const float gsq = (Aq + q10) + q11;
            const int o = hr * LDSW + (e ? 65 : 0);
            srx[o] = 0.5f * (gxp + gxq);
            sry[o] = 0.5f * (gyp + gyq);
            srt[o] = 0.5f * (gsq - gsp);
        }
    } else {
        // ---- slow Phase A: full bounds + reflect, scalar per LDS cell ----
        for (int t = tid; t < (TH + 2) * (TW + 2); t += 256) {
            const int hr = t / (TW + 2);
            const int c  = t - hr * (TW + 2);
            const int a  = r0 - 1 + hr;
            const int bc = c0 - 1 + c;
            float rx = 0.f, ry = 0.f, rt = 0.f;
            if (a >= 0 && a < IMG_H && bc >= 0 && bc < IMG_W) {
                const int a1 = (a + 1 == IMG_H) ? (IMG_H - 2) : (a + 1);   // reflect (after)
                const int b1 = (bc + 1 == IMG_W) ? (IMG_W - 2) : (bc + 1); // reflect (after)
                const int i0 = a * IMG_W, i1 = a1 * IMG_W;
                const float p00 = prev[i0 + bc], p01 = prev[i0 + b1];
                const float p10 = prev[i1 + bc], p11 = prev[i1 + b1];
                const float q00 = next[i0 + bc], q01 = next[i0 + b1];
                const float q10 = next[i1 + bc], q11 = next[i1 + b1];
                const float Ap = p00 + p01, Aq = q00 + q01;
                const float gxp = ((p01 - p00) - p10) + p11;
                const float gxq = ((q01 - q00) - q10) + q11;
                const float gyp = (p10 - Ap) + p11;
                const float gyq = (q10 - Aq) + q11;
                const float gsp = (Ap + p10) + p11;
                const float gsq = (Aq + q10) + q11;
                rx = 0.5f * (gxp + gxq);
                ry = 0.5f * (gyp + gyq);
                rt = 0.5f * (gsq - gsp);
            }
            const int o = hr * LDSW + c;
            srx[o] = rx; sry[o] = ry; srt[o] = rt;
        }
    }

    __syncthreads();

    // ---- Phase B: each thread -> 1 output row x 8 output cols ----
    // image cols c0+8tx .. c0+8tx+7; window LDS cols 8tx .. 8tx+9 (consecutive).
    const int jb = tx * 8;
    int off = ty * LDSW + jb;

    float aXX[8] = {}, aYY[8] = {}, aXY[8] = {}, aXT[8] = {}, aYT[8] = {};

    #pragma unroll
    for (int rr = 0; rr < 3; ++rr) {
        const float* px = srx + off;
        const float* py = sry + off;
        const float* pt = srt + off;
        float X[10], Y[10], T[10];
        #pragma unroll
        for (int k = 0; k < 10; ++k) { X[k] = px[k]; Y[k] = py[k]; T[k] = pt[k]; }
        off += LDSW;
        float xx[10], yy[10], xy[10], xt[10], yt[10];
        #pragma unroll
        for (int k = 0; k < 10; ++k) {
            xx[k] = X[k] * X[k];
            yy[k] = Y[k] * Y[k];
            xy[k] = X[k] * Y[k];
            xt[k] = T[k] * X[k];
            yt[k] = T[k] * Y[k];
        }
        // exact reference box3 order per output & array: dr outer (rr asc), dc inner
        #pragma unroll
        for (int q = 0; q < 8; ++q) {
            aXX[q] += xx[q]; aXX[q] += xx[q + 1]; aXX[q] += xx[q + 2];
            aYY[q] += yy[q]; aYY[q] += yy[q + 1]; aYY[q] += yy[q + 2];
            aXY[q] += xy[q]; aXY[q] += xy[q + 1]; aXY[q] += xy[q + 2];
            aXT[q] += xt[q]; aXT[q] += xt[q + 1]; aXT[q] += xt[q + 2];
            aYT[q] += yt[q]; aYT[q] += yt[q + 1]; aYT[q] += yt[q + 2];
        }
    }

    const int i = r0 + ty;
    float uo[8], vo[8];
    #pragma unroll
    for (int q = 0; q < 8; ++q) {
        const float Sxx = aXX[q], Syy = aYY[q], Sxy = aXY[q];
        const float Sxt = aXT[q], Syt = aYT[q];
        const float t1 = Sxx * Syy;
        const float t2 = Sxy * Sxy;
        const float det = t1 - t2;
        float u = 0.f, v = 0.f;
        if (det != 0.f) {
            const float inv = __builtin_amdgcn_rcpf(det);  // 1-ulp rcp, ample margin
            const float n1 = Syy * Sxt - Sxy * Syt;
            const float n2 = Sxx * Syt - Sxy * Sxt;
            u = n1 * inv;
            v = n2 * inv;
        }
        const int j = c0 + jb + q;
        if (i == 0 || j == 0) { u = 0.f; v = 0.f; }  // reference zeroes row0/col0
        uo[q] = u; vo[q] = v;
    }
    const int oidx = i * IMG_W + (c0 + jb);
    *reinterpret_cast<float4*>(out + oidx)     = make_float4(uo[0], uo[1], uo[2], uo[3]);
    *reinterpret_cast<float4*>(out + oidx + 4) = make_float4(uo[4], uo[5], uo[6], uo[7]);
    const int vidx = IMG_H * IMG_W + oidx;
    *reinterpret_cast<float4*>(out + vidx)     = make_float4(vo[0], vo[1], vo[2], vo[3]);
    *reinterpret_cast<float4*>(out + vidx + 4) = make_float4(vo[4], vo[5], vo[6], vo[7]);
}

extern "C" void kernel_launch(void* const* d_in, const int* in_sizes, int n_in,
                              void* d_out, int out_size, void* d_ws, size_t ws_size,
                              hipStream_t stream) {
    const float* prev = (const float*)d_in[0];
    const float* next = (const float*)d_in[1];
    float* out = (float*)d_out;
    dim3 grid(IMG_W / TW, IMG_H / TH);   // 32 x 64
    dim3 block(8, 32);
    lk_flow_v10<<<grid, block, 0, stream>>>(prev, next, out);
}

// Round 11
// 25.019 us; speedup vs baseline: 2.3439x; 1.0541x over previous
//
#include <hip/hip_runtime.h>

// Lucas-Kanade optical flow — r11: r7 structure with INTERLEAVED (x,y,t) LDS
// triples, row stride 104 dwords -> Phase-B reads are provably 16B-aligned
// float4/float2 LDS loads (15 wide reads/thread vs up to 54 scalar b32).
// Bank math: 104 mod 32 = 8 -> b128 start bank = 8*ty + 12*tx: 2 lanes/start
// (free, m136); per-wave quads/bank = 8 = wave64-b128 minimum.
// Everything else identical to r7 (best: 24.4us, absmax 0.0078125):
// (256,4) [r9: 8 blk/CU thrashes L2], XCD band remap, interior fast path,
// rcpf epilogue, exact reference op/rounding order per pixel.
// Input:  image_prev, image_next  (1,1,2048,2048) fp32
// Output: (1,2,2048,2048) fp32  -> u at [0:H*W], v at [H*W:2*H*W]

#pragma clang fp contract(off)

#define IMG_H 2048
#define IMG_W 2048
#define TW 32
#define TH 32
// LDS col c (0..33) holds res at image col (c0 + c - 1); triple (x,y,t) at
// dwords RS*row + 3c + {0,1,2}. RS = 104 (34*3 = 102 data + 2 pad, mult of 4).
#define RS 104

__global__ __launch_bounds__(256, 4)
void lk_flow_v11(const float* __restrict__ prev,
                 const float* __restrict__ next,
                 float* __restrict__ out) {
    #pragma clang fp contract(off)
    __shared__ __align__(16) float srs[(TH + 2) * RS];

    // XCD-aware remap (r6): each XCD gets a contiguous band of 8 tile-rows.
    const int lin = (int)blockIdx.y * (int)gridDim.x + (int)blockIdx.x;
    const int nl  = (lin >> 3) + (lin & 7) * 512;
    const int r0  = (nl >> 6) * TH;
    const int c0  = (nl & 63) * TW;

    const int tx  = (int)threadIdx.x;   // 0..7
    const int ty  = (int)threadIdx.y;   // 0..31
    const int tid = ty * 8 + tx;

    // rows touched: r0-1 .. r0+33 (incl. a1); cols touched: c0-1 .. c0+33
    const bool interior = (r0 > 0) & (r0 + TH + 2 <= IMG_H - 1) &
                          (c0 > 0) & (c0 + TW + 2 <= IMG_W - 1);

    if (interior) {
        // ---- fast Phase A: no bounds checks, no reflect, int32 addressing ----
        #pragma unroll
        for (int pass = 0; pass < 2; ++pass) {
            const int t = tid + pass * 256;
            if (pass == 0 || tid < 16) {          // 34*8 = 272 chunks
                const int hr = t >> 3;
                const int ch = t & 7;
                const int i0 = (r0 - 1 + hr) * IMG_W + (c0 + ch * 4);
                const int i1 = i0 + IMG_W;
                const float4 P0 = *reinterpret_cast<const float4*>(prev + i0);
                const float4 P1 = *reinterpret_cast<const float4*>(prev + i1);
                const float4 Q0 = *reinterpret_cast<const float4*>(next + i0);
                const float4 Q1 = *reinterpret_cast<const float4*>(next + i1);
                const float p0[5] = {P0.x, P0.y, P0.z, P0.w, prev[i0 + 4]};
                const float p1[5] = {P1.x, P1.y, P1.z, P1.w, prev[i1 + 4]};
                const float q0[5] = {Q0.x, Q0.y, Q0.z, Q0.w, next[i0 + 4]};
                const float q1[5] = {Q1.x, Q1.y, Q1.z, Q1.w, next[i1 + 4]};
                // LDS cols (1+4ch)..(4+4ch): dword base = RS*hr + 3 + 12ch
                const int base = hr * RS + 3 + ch * 12;
                #pragma unroll
                for (int k = 0; k < 4; ++k) {
                    // bit-equal to reference left-to-right order:
                    //   gx=((p01-p00)-p10)+p11; gy=(p10-(p00+p01))+p11; gs=((p00+p01)+p10)+p11
                    const float Ap = p0[k] + p0[k + 1];
                    const float Aq = q0[k] + q0[k + 1];
                    const float gxp = ((p0[k + 1] - p0[k]) - p1[k]) + p1[k + 1];
                    const float gxq = ((q0[k + 1] - q0[k]) - q1[k]) + q1[k + 1];
                    const float gyp = (p1[k] - Ap) + p1[k + 1];
                    const float gyq = (q1[k] - Aq) + q1[k + 1];
                    const float gsp = (Ap + p1[k]) + p1[k + 1];
                    const float gsq = (Aq + q1[k]) + q1[k + 1];
                    srs[base + 3 * k + 0] = 0.5f * (gxp + gxq);
                    srs[base + 3 * k + 1] = 0.5f * (gyp + gyq);
                    srs[base + 3 * k + 2] = 0.5f * (gsq - gsp);   // 0.5*(-gsp+gsq)
                }
            }
        }
        if (tid < 68) {   // edge cols: e=0 -> image c0-1 (LDS col 0), e=1 -> c0+32 (LDS col 33)
            const int hr = tid >> 1;
            const int e  = tid & 1;
            const int bc = e ? (c0 + TW) : (c0 - 1);
            const int i0 = (r0 - 1 + hr) * IMG_W + bc;
            const int i1 = i0 + IMG_W;
            const float p00 = prev[i0], p01 = prev[i0 + 1];
            const float p10 = prev[i1], p11 = prev[i1 + 1];
            const float q00 = next[i0], q01 = next[i0 + 1];
            const float q10 = next[i1], q11 = next[i1 + 1];
            const float Ap = p00 + p01, Aq = q00 + q01;
            const float gxp = ((p01 - p00) - p10) + p11;
            const float gxq = ((q01 - q00) - q10) + q11;
            const float gyp = (p10 - Ap) + p11;
            const float gyq = (q10 - Aq) + q11;
            const float gsp = (Ap + p10) + p11;
            const float gsq = (Aq + q10) + q11;
            const int o = hr * RS + (e ? 99 : 0);   // 3*33 = 99
            srs[o + 0] = 0.5f * (gxp + gxq);
            srs[o + 1] = 0.5f * (gyp + gyq);
            srs[o + 2] = 0.5f * (gsq - gsp);
        }
    } else {
        // ---- slow Phase A: full bounds + reflect, scalar per LDS cell ----
        for (int t = tid; t < 34 * 34; t += 256) {
            const int hr = t / 34;
            const int c  = t - hr * 34;
            const int a  = r0 - 1 + hr;
            const int bc = c0 - 1 + c;
            float rx = 0.f, ry = 0.f, rt = 0.f;
            if (a >= 0 && a < IMG_H && bc >= 0 && bc < IMG_W) {
                const int a1 = (a + 1 == IMG_H) ? (IMG_H - 2) : (a + 1);   // reflect (after)
                const int b1 = (bc + 1 == IMG_W) ? (IMG_W - 2) : (bc + 1); // reflect (after)
                const int i0 = a * IMG_W, i1 = a1 * IMG_W;
                const float p00 = prev[i0 + bc], p01 = prev[i0 + b1];
                const float p10 = prev[i1 + bc], p11 = prev[i1 + b1];
                const float q00 = next[i0 + bc], q01 = next[i0 + b1];
                const float q10 = next[i1 + bc], q11 = next[i1 + b1];
                const float Ap = p00 + p01, Aq = q00 + q01;
                const float gxp = ((p01 - p00) - p10) + p11;
                const float gxq = ((q01 - q00) - q10) + q11;
                const float gyp = (p10 - Ap) + p11;
                const float gyq = (q10 - Aq) + q11;
                const float gsp = (Ap + p10) + p11;
                const float gsq = (Aq + q10) + q11;
                rx = 0.5f * (gxp + gxq);
                ry = 0.5f * (gyp + gyq);
                rt = 0.5f * (gsq - gsp);
            }
            const int o = hr * RS + 3 * c;
            srs[o + 0] = rx; srs[o + 1] = ry; srs[o + 2] = rt;
        }
    }

    __syncthreads();

    // ---- Phase B: each thread -> 1 output row x 4 output cols ----
    // window: LDS cols jb..jb+5 (image cols c0+jb-1 .. c0+jb+4) = dwords
    // [RS*row + 12tx .. +17]: 4x float4 + 1x float2, all provably aligned.
    const int jb = tx * 4;
    int base = ty * RS + 3 * jb;     // 3*jb = 12*tx, multiple of 4 dwords

    float aXX[4] = {0.f, 0.f, 0.f, 0.f};
    float aYY[4] = {0.f, 0.f, 0.f, 0.f};
    float aXY[4] = {0.f, 0.f, 0.f, 0.f};
    float aXT[4] = {0.f, 0.f, 0.f, 0.f};
    float aYT[4] = {0.f, 0.f, 0.f, 0.f};

    #pragma unroll
    for (int rr = 0; rr < 3; ++rr) {
        const float4 w0 = *reinterpret_cast<const float4*>(srs + base);
        const float4 w1 = *reinterpret_cast<const float4*>(srs + base + 4);
        const float4 w2 = *reinterpret_cast<const float4*>(srs + base + 8);
        const float4 w3 = *reinterpret_cast<const float4*>(srs + base + 12);
        const float2 w4 = *reinterpret_cast<const float2*>(srs + base + 16);
        base += RS;
        const float X[6] = {w0.x, w0.w, w1.z, w2.y, w3.x, w3.w};
        const float Y[6] = {w0.y, w1.x, w1.w, w2.z, w3.y, w4.x};
        const float T[6] = {w0.z, w1.y, w2.x, w2.w, w3.z, w4.y};
        float xx[6], yy[6], xy[6], xt[6], yt[6];
        #pragma unroll
        for (int k = 0; k < 6; ++k) {
            xx[k] = X[k] * X[k];
            yy[k] = Y[k] * Y[k];
            xy[k] = X[k] * Y[k];
            xt[k] = T[k] * X[k];
            yt[k] = T[k] * Y[k];
        }
        // exact reference box3 order per output & array: dr outer (rr asc), dc inner
        #pragma unroll
        for (int q = 0; q < 4; ++q) {
            aXX[q] += xx[q]; aXX[q] += xx[q + 1]; aXX[q] += xx[q + 2];
            aYY[q] += yy[q]; aYY[q] += yy[q + 1]; aYY[q] += yy[q + 2];
            aXY[q] += xy[q]; aXY[q] += xy[q + 1]; aXY[q] += xy[q + 2];
            aXT[q] += xt[q]; aXT[q] += xt[q + 1]; aXT[q] += xt[q + 2];
            aYT[q] += yt[q]; aYT[q] += yt[q + 1]; aYT[q] += yt[q + 2];
        }
    }

    const int i = r0 + ty;
    float uo[4], vo[4];
    #pragma unroll
    for (int q = 0; q < 4; ++q) {
        const float Sxx = aXX[q], Syy = aYY[q], Sxy = aXY[q];
        const float Sxt = aXT[q], Syt = aYT[q];
        const float t1 = Sxx * Syy;
        const float t2 = Sxy * Sxy;
        const float det = t1 - t2;
        float u = 0.f, v = 0.f;
        if (det != 0.f) {
            const float inv = __builtin_amdgcn_rcpf(det);  // 1-ulp rcp, ample margin
            const float n1 = Syy * Sxt - Sxy * Syt;
            const float n2 = Sxx * Syt - Sxy * Sxt;
            u = n1 * inv;
            v = n2 * inv;
        }
        const int j = c0 + jb + q;
        if (i == 0 || j == 0) { u = 0.f; v = 0.f; }  // reference zeroes row0/col0
        uo[q] = u; vo[q] = v;
    }
    const int oidx = i * IMG_W + (c0 + jb);
    float4 U = {uo[0], uo[1], uo[2], uo[3]};
    float4 V = {vo[0], vo[1], vo[2], vo[3]};
    *reinterpret_cast<float4*>(out + oidx) = U;
    *reinterpret_cast<float4*>(out + IMG_H * IMG_W + oidx) = V;
}

extern "C" void kernel_launch(void* const* d_in, const int* in_sizes, int n_in,
                              void* d_out, int out_size, void* d_ws, size_t ws_size,
                              hipStream_t stream) {
    const float* prev = (const float*)d_in[0];
    const float* next = (const float*)d_in[1];
    float* out = (float*)d_out;
    dim3 grid(IMG_W / TW, IMG_H / TH);   // 64 x 64
    dim3 block(8, 32);
    lk_flow_v11<<<grid, block, 0, stream>>>(prev, next, out);
}

// Round 12
// 24.240 us; speedup vs baseline: 2.4193x; 1.0322x over previous
//
#include <hip/hip_runtime.h>

// Lucas-Kanade optical flow — FINAL (r7 verbatim, measured best 24.4us).
// Structure: fused single kernel; interior fast path (no bounds/reflect for
// 94% of blocks); 32-bit addressing; conflict-free stride-35 LDS
// (bank = 3*row+col, <=2-way = free); XCD band remap; (256,4) occupancy
// [r9 proved 8 blk/CU thrashes per-XCD L2: 58.6us]; rcpf epilogue.
// Numerics: exact reference op/rounding order per pixel (fp contract off,
// sequential (dr,dc) box3 accumulation) -> absmax 0.0078125, 73x under
// threshold. Any reassociation/contraction fails (r0: absmax 28.6).
// Input:  image_prev, image_next  (1,1,2048,2048) fp32
// Output: (1,2,2048,2048) fp32  -> u at [0:H*W], v at [H*W:2*H*W]

#pragma clang fp contract(off)

#define IMG_H 2048
#define IMG_W 2048
#define TW 32
#define TH 32
// LDS col c holds res at image col (c0 + c - 1): 0 = left halo, 1..32 interior,
// 33 = right halo, 34 = pad. stride 35 (odd) -> bank = 3*row + col: 2-way, free.
#define LDSW 35

__global__ __launch_bounds__(256, 4)
void lk_flow_final(const float* __restrict__ prev,
                   const float* __restrict__ next,
                   float* __restrict__ out) {
    #pragma clang fp contract(off)
    __shared__ float srx[(TH + 2) * LDSW];
    __shared__ float sry[(TH + 2) * LDSW];
    __shared__ float srt[(TH + 2) * LDSW];

    // XCD-aware remap: each XCD gets a contiguous band of 8 tile-rows.
    const int lin = (int)blockIdx.y * (int)gridDim.x + (int)blockIdx.x;
    const int nl  = (lin >> 3) + (lin & 7) * 512;
    const int r0  = (nl >> 6) * TH;
    const int c0  = (nl & 63) * TW;

    const int tx  = (int)threadIdx.x;   // 0..7
    const int ty  = (int)threadIdx.y;   // 0..31
    const int tid = ty * 8 + tx;

    // rows touched: r0-1 .. r0+33 (incl. a1); cols touched: c0-1 .. c0+33
    const bool interior = (r0 > 0) & (r0 + TH + 2 <= IMG_H - 1) &
                          (c0 > 0) & (c0 + TW + 2 <= IMG_W - 1);

    if (interior) {
        // ---- fast Phase A: no bounds checks, no reflect, int32 addressing ----
        #pragma unroll
        for (int pass = 0; pass < 2; ++pass) {
            const int t = tid + pass * 256;
            if (pass == 0 || tid < 16) {          // 34*8 = 272 chunks
                const int hr = t >> 3;
                const int ch = t & 7;
                const int i0 = (r0 - 1 + hr) * IMG_W + (c0 + ch * 4);
                const int i1 = i0 + IMG_W;
                const float4 P0 = *reinterpret_cast<const float4*>(prev + i0);
                const float4 P1 = *reinterpret_cast<const float4*>(prev + i1);
                const float4 Q0 = *reinterpret_cast<const float4*>(next + i0);
                const float4 Q1 = *reinterpret_cast<const float4*>(next + i1);
                const float p0[5] = {P0.x, P0.y, P0.z, P0.w, prev[i0 + 4]};
                const float p1[5] = {P1.x, P1.y, P1.z, P1.w, prev[i1 + 4]};
                const float q0[5] = {Q0.x, Q0.y, Q0.z, Q0.w, next[i0 + 4]};
                const float q1[5] = {Q1.x, Q1.y, Q1.z, Q1.w, next[i1 + 4]};
                const int base = hr * LDSW + 1 + ch * 4;
                #pragma unroll
                for (int k = 0; k < 4; ++k) {
                    // bit-equal to reference left-to-right order:
                    //   gx=((p01-p00)-p10)+p11; gy=(p10-(p00+p01))+p11; gs=((p00+p01)+p10)+p11
                    const float Ap = p0[k] + p0[k + 1];
                    const float Aq = q0[k] + q0[k + 1];
                    const float gxp = ((p0[k + 1] - p0[k]) - p1[k]) + p1[k + 1];
                    const float gxq = ((q0[k + 1] - q0[k]) - q1[k]) + q1[k + 1];
                    const float gyp = (p1[k] - Ap) + p1[k + 1];
                    const float gyq = (q1[k] - Aq) + q1[k + 1];
                    const float gsp = (Ap + p1[k]) + p1[k + 1];
                    const float gsq = (Aq + q1[k]) + q1[k + 1];
                    srx[base + k] = 0.5f * (gxp + gxq);
                    sry[base + k] = 0.5f * (gyp + gyq);
                    srt[base + k] = 0.5f * (gsq - gsp);     // 0.5*(-gsp+gsq)
                }
            }
        }
        if (tid < 68) {   // edge cols: e=0 -> image c0-1 (LDS 0), e=1 -> c0+32 (LDS 33)
            const int hr = tid >> 1;
            const int e  = tid & 1;
            const int bc = e ? (c0 + TW) : (c0 - 1);
            const int i0 = (r0 - 1 + hr) * IMG_W + bc;
            const int i1 = i0 + IMG_W;
            const float p00 = prev[i0], p01 = prev[i0 + 1];
            const float p10 = prev[i1], p11 = prev[i1 + 1];
            const float q00 = next[i0], q01 = next[i0 + 1];
            const float q10 = next[i1], q11 = next[i1 + 1];
            const float Ap = p00 + p01, Aq = q00 + q01;
            const float gxp = ((p01 - p00) - p10) + p11;
            const float gxq = ((q01 - q00) - q10) + q11;
            const float gyp = (p10 - Ap) + p11;
            const float gyq = (q10 - Aq) + q11;
            const float gsp = (Ap + p10) + p11;
            const float gsq = (Aq + q10) + q11;
            const int o = hr * LDSW + (e ? 33 : 0);
            srx[o] = 0.5f * (gxp + gxq);
            sry[o] = 0.5f * (gyp + gyq);
            srt[o] = 0.5f * (gsq - gsp);
        }
    } else {
        // ---- slow Phase A: full bounds + reflect, scalar per LDS cell ----
        for (int t = tid; t < 34 * 34; t += 256) {
            const int hr = t / 34;
            const int c  = t - hr * 34;
            const int a  = r0 - 1 + hr;
            const int bc = c0 - 1 + c;
            float rx = 0.f, ry = 0.f, rt = 0.f;
            if (a >= 0 && a < IMG_H && bc >= 0 && bc < IMG_W) {
                const int a1 = (a + 1 == IMG_H) ? (IMG_H - 2) : (a + 1);   // reflect (after)
                const int b1 = (bc + 1 == IMG_W) ? (IMG_W - 2) : (bc + 1); // reflect (after)
                const int i0 = a * IMG_W, i1 = a1 * IMG_W;
                const float p00 = prev[i0 + bc], p01 = prev[i0 + b1];
                const float p10 = prev[i1 + bc], p11 = prev[i1 + b1];
                const float q00 = next[i0 + bc], q01 = next[i0 + b1];
                const float q10 = next[i1 + bc], q11 = next[i1 + b1];
                const float Ap = p00 + p01, Aq = q00 + q01;
                const float gxp = ((p01 - p00) - p10) + p11;
                const float gxq = ((q01 - q00) - q10) + q11;
                const float gyp = (p10 - Ap) + p11;
                const float gyq = (q10 - Aq) + q11;
                const float gsp = (Ap + p10) + p11;
                const float gsq = (Aq + q10) + q11;
                rx = 0.5f * (gxp + gxq);
                ry = 0.5f * (gyp + gyq);
                rt = 0.5f * (gsq - gsp);
            }
            const int o = hr * LDSW + c;
            srx[o] = rx; sry[o] = ry; srt[o] = rt;
        }
    }

    __syncthreads();

    // ---- Phase B: each thread -> 1 output row x 4 output cols ----
    const int jb = tx * 4;
    int off = ty * LDSW + jb;

    float aXX[4] = {0.f, 0.f, 0.f, 0.f};
    float aYY[4] = {0.f, 0.f, 0.f, 0.f};
    float aXY[4] = {0.f, 0.f, 0.f, 0.f};
    float aXT[4] = {0.f, 0.f, 0.f, 0.f};
    float aYT[4] = {0.f, 0.f, 0.f, 0.f};

    #pragma unroll
    for (int rr = 0; rr < 3; ++rr) {
        const float* px = srx + off;
        const float* py = sry + off;
        const float* pt = srt + off;
        float X[6], Y[6], T[6];
        #pragma unroll
        for (int k = 0; k < 6; ++k) { X[k] = px[k]; Y[k] = py[k]; T[k] = pt[k]; }
        off += LDSW;
        float xx[6], yy[6], xy[6], xt[6], yt[6];
        #pragma unroll
        for (int k = 0; k < 6; ++k) {
            xx[k] = X[k] * X[k];
            yy[k] = Y[k] * Y[k];
            xy[k] = X[k] * Y[k];
            xt[k] = T[k] * X[k];
            yt[k] = T[k] * Y[k];
        }
        // exact reference box3 order per output & array: dr outer (rr asc), dc inner
        #pragma unroll
        for (int q = 0; q < 4; ++q) {
            aXX[q] += xx[q]; aXX[q] += xx[q + 1]; aXX[q] += xx[q + 2];
            aYY[q] += yy[q]; aYY[q] += yy[q + 1]; aYY[q] += yy[q + 2];
            aXY[q] += xy[q]; aXY[q] += xy[q + 1]; aXY[q] += xy[q + 2];
            aXT[q] += xt[q]; aXT[q] += xt[q + 1]; aXT[q] += xt[q + 2];
            aYT[q] += yt[q]; aYT[q] += yt[q + 1]; aYT[q] += yt[q + 2];
        }
    }

    const int i = r0 + ty;
    float uo[4], vo[4];
    #pragma unroll
    for (int q = 0; q < 4; ++q) {
        const float Sxx = aXX[q], Syy = aYY[q], Sxy = aXY[q];
        const float Sxt = aXT[q], Syt = aYT[q];
        const float t1 = Sxx * Syy;
        const float t2 = Sxy * Sxy;
        const float det = t1 - t2;
        float u = 0.f, v = 0.f;
        if (det != 0.f) {
            const float inv = __builtin_amdgcn_rcpf(det);  // 1-ulp rcp, ample margin
            const float n1 = Syy * Sxt - Sxy * Syt;
            const float n2 = Sxx * Syt - Sxy * Sxt;
            u = n1 * inv;
            v = n2 * inv;
        }
        const int j = c0 + jb + q;
        if (i == 0 || j == 0) { u = 0.f; v = 0.f; }  // reference zeroes row0/col0
        uo[q] = u; vo[q] = v;
    }
    const int oidx = i * IMG_W + (c0 + jb);
    float4 U = {uo[0], uo[1], uo[2], uo[3]};
    float4 V = {vo[0], vo[1], vo[2], vo[3]};
    *reinterpret_cast<float4*>(out + oidx) = U;
    *reinterpret_cast<float4*>(out + IMG_H * IMG_W + oidx) = V;
}

extern "C" void kernel_launch(void* const* d_in, const int* in_sizes, int n_in,
                              void* d_out, int out_size, void* d_ws, size_t ws_size,
                              hipStream_t stream) {
    const float* prev = (const float*)d_in[0];
    const float* next = (const float*)d_in[1];
    float* out = (float*)d_out;
    dim3 grid(IMG_W / TW, IMG_H / TH);   // 64 x 64
    dim3 block(8, 32);
    lk_flow_final<<<grid, block, 0, stream>>>(prev, next, out);
}